// Round 13
// baseline (495.573 us; speedup 1.0000x reference)
//
#include <hip/hip_runtime.h>
#include <hip/hip_fp16.h>
#include <math.h>

// ---------------------------------------------------------------------------
// GAT graph encoder: 2x GATConv (PyG semantics, add_self_loops=False)
// R16->R17: R16 GEMM2-fusion reverted (k_agg_g2 88.3 vs 71.6; occupancy
//   74->48%; GEMM2 itself proved only ~7-15us -> remainder is CSR-heavy,
//   est. 100-150us of 197). NEW: 4-kernel bucket-sort CSR replaced with
//   lean 3-pass build: k_count (global atomics on N counters, L2-resident)
//   -> hierarchical exclusive scan (k_ssum/k_stop/k_sfin, proven
//   Hillis-Steele pattern) -> k_scatter (direct esrc scatter via
//   atomicAdd(cur[dst])). Edge passes 3->2, no tmp buffer, no LDS
//   histogram serialization. Edge order within node remains arbitrary
//   (atomic race, tolerance-tested as before).
//   k_agg (R15 form, both layers) + both GEMMs (R12 form) unchanged.
// ---------------------------------------------------------------------------

typedef _Float16 f16x8 __attribute__((ext_vector_type(8)));
typedef float    f32x4 __attribute__((ext_vector_type(4)));

// ---------------- CSR build (R17 lean form) ----------------

__global__ __launch_bounds__(256) void k_count(const int* __restrict__ dst,
                                               int* __restrict__ cnt, int E) {
    for (int e = blockIdx.x * 256 + threadIdx.x; e < E; e += gridDim.x * 256)
        atomicAdd(&cnt[dst[e]], 1);
}

// per-1024-chunk sums
__global__ void k_ssum(const int* __restrict__ cnt, int* __restrict__ bsum, int N) {
    __shared__ int sd[1024];
    int t = threadIdx.x;
    int i = blockIdx.x * 1024 + t;
    sd[t] = (i < N) ? cnt[i] : 0;
    __syncthreads();
    for (int ofs = 512; ofs > 0; ofs >>= 1) {
        if (t < ofs) sd[t] += sd[t + ofs];
        __syncthreads();
    }
    if (t == 0) bsum[blockIdx.x] = sd[0];
}

// exclusive scan of chunk sums (nb <= 1024)
__global__ void k_stop(const int* __restrict__ bsum, int* __restrict__ bbase,
                       int nb, int N, int E, int* __restrict__ off) {
    __shared__ int sd[1024];
    int t = threadIdx.x;
    int v = (t < nb) ? bsum[t] : 0;
    sd[t] = v; __syncthreads();
    for (int ofs = 1; ofs < 1024; ofs <<= 1) {
        int w = (t >= ofs) ? sd[t - ofs] : 0;
        __syncthreads();
        sd[t] += w;
        __syncthreads();
    }
    if (t < nb) bbase[t] = sd[t] - v;
    if (t == 0) off[N] = E;
}

// per-chunk exclusive scan + base -> off, cur
__global__ void k_sfin(const int* __restrict__ cnt, const int* __restrict__ bbase,
                       int* __restrict__ off, int* __restrict__ cur, int N) {
    __shared__ int sd[1024];
    int t = threadIdx.x;
    int i = blockIdx.x * 1024 + t;
    int v = (i < N) ? cnt[i] : 0;
    sd[t] = v; __syncthreads();
    for (int ofs = 1; ofs < 1024; ofs <<= 1) {
        int w = (t >= ofs) ? sd[t - ofs] : 0;
        __syncthreads();
        sd[t] += w;
        __syncthreads();
    }
    if (i < N) {
        int ex = bbase[blockIdx.x] + sd[t] - v;
        off[i] = ex;
        cur[i] = ex;
    }
}

__global__ __launch_bounds__(256) void k_scatter(
    const int* __restrict__ src, const int* __restrict__ dst,
    int* __restrict__ cur, int* __restrict__ esrc, int E) {
    for (int e = blockIdx.x * 256 + threadIdx.x; e < E; e += gridDim.x * 256) {
        int p = atomicAdd(&cur[dst[e]], 1);
        esrc[p] = src[e];
    }
}

// ---------------- MFMA GEMM + fused attention dots (R12 form) ----------------
// Y(fp16)[N,128] = cast16(X[N,128]) @ cast16(W[128,128]); fp32 accum.
// A-frag: m=lane&15 (row), k=(lane>>4)*8+j. B-frag: n=lane&15 (col), same k.
// C/D: col=lane&15, row=(lane>>4)*4+reg.
// W in LDS fragment-major; streamed B-frags; 3 blocks/CU.

template <int H, typename TI>
__global__ __launch_bounds__(256, 3) void k_gemm_mfma(
    const TI* __restrict__ X, const float* __restrict__ Wg,
    const float* __restrict__ att_s, const float* __restrict__ att_d,
    __half* __restrict__ Y, float* __restrict__ as_, float* __restrict__ ad_, int N)
{
    __shared__ _Float16 Wf[8][4][512];   // [nt][ks][lane*8+j], 32 KB
    __shared__ _Float16 Xh[64][136];     // +8 pad: breaks 256B-stride bank clash
    const int t = threadIdx.x;
    const int lane = t & 63;
    const int wv = t >> 6;
    const int m = lane & 15;
    const int q = lane >> 4;

    // stage W fp32 -> fp16 fragment-major: 2048 fragments, 8 per thread.
    for (int f = t; f < 2048; f += 256) {
        int nt = f >> 8, ks = (f >> 6) & 3, ls = f & 63;
        int qq = ls >> 4, mm = ls & 15;
        int col = nt * 16 + mm;
        int k0  = ks * 32 + qq * 8;
        f16x8 frag;
#pragma unroll
        for (int j = 0; j < 8; j++)
            frag[j] = (_Float16)Wg[(size_t)(k0 + j) * 128 + col];
        *(f16x8*)&Wf[nt][ks][ls * 8] = frag;
    }

    float atts_v[8], attd_v[8];
#pragma unroll
    for (int nt = 0; nt < 8; nt++) {
        atts_v[nt] = att_s[nt * 16 + m];
        attd_v[nt] = att_d[nt * 16 + m];
    }
    __syncthreads();

    for (int base = blockIdx.x * 64; base < N; base += gridDim.x * 64) {
        for (int i = t; i < 1024; i += 256) {
            int r = i >> 4, c8 = i & 15;
            int gr = base + r;
            _Float16* d = &Xh[r][c8 * 8];
            if (gr < N) {
                if constexpr (sizeof(TI) == 4) {
                    const float4* s = (const float4*)((const float*)X + (size_t)gr * 128 + c8 * 8);
                    float4 x0 = s[0], x1 = s[1];
                    d[0] = (_Float16)x0.x; d[1] = (_Float16)x0.y;
                    d[2] = (_Float16)x0.z; d[3] = (_Float16)x0.w;
                    d[4] = (_Float16)x1.x; d[5] = (_Float16)x1.y;
                    d[6] = (_Float16)x1.z; d[7] = (_Float16)x1.w;
                } else {
                    *(uint4*)d = *(const uint4*)((const __half*)X + (size_t)gr * 128 + c8 * 8);
                }
            } else {
                uint4 z; z.x = 0; z.y = 0; z.z = 0; z.w = 0;
                *(uint4*)d = z;
            }
        }
        __syncthreads();

        const int rowb = base + wv * 16;

        f16x8 af[4];
#pragma unroll
        for (int ks = 0; ks < 4; ks++)
            af[ks] = *(const f16x8*)&Xh[wv * 16 + m][ks * 32 + q * 8];

        f32x4 acc[8];
#pragma unroll
        for (int nt = 0; nt < 8; nt++) { acc[nt][0] = 0.f; acc[nt][1] = 0.f; acc[nt][2] = 0.f; acc[nt][3] = 0.f; }

#pragma unroll
        for (int nt = 0; nt < 8; nt++) {
            f16x8 b0v = *(const f16x8*)&Wf[nt][0][lane * 8];
            f16x8 b1v = *(const f16x8*)&Wf[nt][1][lane * 8];
            f16x8 b2v = *(const f16x8*)&Wf[nt][2][lane * 8];
            f16x8 b3v = *(const f16x8*)&Wf[nt][3][lane * 8];
            acc[nt] = __builtin_amdgcn_mfma_f32_16x16x32_f16(af[0], b0v, acc[nt], 0, 0, 0);
            acc[nt] = __builtin_amdgcn_mfma_f32_16x16x32_f16(af[1], b1v, acc[nt], 0, 0, 0);
            acc[nt] = __builtin_amdgcn_mfma_f32_16x16x32_f16(af[2], b2v, acc[nt], 0, 0, 0);
            acc[nt] = __builtin_amdgcn_mfma_f32_16x16x32_f16(af[3], b3v, acc[nt], 0, 0, 0);
        }

#pragma unroll
        for (int nt = 0; nt < 8; nt++) {
#pragma unroll
            for (int i = 0; i < 4; i++) {
                int r = rowb + q * 4 + i;
                if (r < N) Y[(size_t)r * 128 + nt * 16 + m] = __float2half(acc[nt][i]);
            }
        }

        if (H == 4) {
            float ph[4][4], pdv[4][4];
#pragma unroll
            for (int h = 0; h < 4; h++)
#pragma unroll
                for (int i = 0; i < 4; i++) {
                    ph[h][i]  = acc[2 * h][i] * atts_v[2 * h] + acc[2 * h + 1][i] * atts_v[2 * h + 1];
                    pdv[h][i] = acc[2 * h][i] * attd_v[2 * h] + acc[2 * h + 1][i] * attd_v[2 * h + 1];
                }
#pragma unroll
            for (int lvl = 0; lvl < 4; lvl++) {
                const int msk = 1 << lvl;
#pragma unroll
                for (int h = 0; h < 4; h++)
#pragma unroll
                    for (int i = 0; i < 4; i++) {
                        ph[h][i]  += __shfl_xor(ph[h][i], msk, 64);
                        pdv[h][i] += __shfl_xor(pdv[h][i], msk, 64);
                    }
            }
            if (m == 0) {
#pragma unroll
                for (int i = 0; i < 4; i++) {
                    int r = rowb + q * 4 + i;
                    if (r < N) {
#pragma unroll
                        for (int h = 0; h < 4; h++) {
                            as_[(size_t)r * 4 + h] = ph[h][i];
                            ad_[(size_t)r * 4 + h] = pdv[h][i];
                        }
                    }
                }
            }
        } else {
            float ps[4], pdv[4];
#pragma unroll
            for (int i = 0; i < 4; i++) {
                float s = 0.f, dsum = 0.f;
#pragma unroll
                for (int nt = 0; nt < 8; nt++) {
                    s    += acc[nt][i] * atts_v[nt];
                    dsum += acc[nt][i] * attd_v[nt];
                }
                ps[i] = s; pdv[i] = dsum;
            }
#pragma unroll
            for (int lvl = 0; lvl < 4; lvl++) {
                const int msk = 1 << lvl;
#pragma unroll
                for (int i = 0; i < 4; i++) {
                    ps[i]  += __shfl_xor(ps[i], msk, 64);
                    pdv[i] += __shfl_xor(pdv[i], msk, 64);
                }
            }
            if (m == 0) {
#pragma unroll
                for (int i = 0; i < 4; i++) {
                    int r = rowb + q * 4 + i;
                    if (r < N) { as_[r] = ps[i]; ad_[r] = pdv[i]; }
                }
            }
        }
        __syncthreads();
    }
}

// ---------------- aggregation: one wave per dst node (R15 form) ----------------
// 16 lanes per edge at 16B/lane; batches of 16 edges, 4 uint4 loads issued
// before consumption; tail predicated. Accumulator = 8 named scalars (no
// alloca -> no PromoteAlloca-to-LDS). Wave-parallel epilogue: each lane
// finalizes 2 cols via cndmask selection on SSA scalars. Cheap ELU.

template <int H, typename TO>
__global__ __launch_bounds__(256) void k_agg(
    const __half* __restrict__ feat,  // [N,128] fp16
    const float* __restrict__ asrc,   // [N,H]
    const float* __restrict__ adst,   // [N,H]
    const int*   __restrict__ off,    // [N+1]
    const int*   __restrict__ esrc,   // [E]
    const float* __restrict__ bias,   // [128]
    TO*          __restrict__ out,    // [N,128]
    int N)
{
    __shared__ __attribute__((aligned(16))) int   sj[4][64];
    __shared__ __attribute__((aligned(16))) float sp[4][64 * H];  // head-major

    int wave = threadIdx.x >> 6;
    int lane = threadIdx.x & 63;
    int node = (blockIdx.x * 256 + threadIdx.x) >> 6;
    if (node >= N) return;
    int beg = off[node], end = off[node + 1];

    float adst_i[H];
#pragma unroll
    for (int h = 0; h < H; h++) adst_i[h] = adst[(size_t)node * H + h];

    const int g    = lane >> 4;                    // edge sub-slot 0..3
    const int sub  = lane & 15;                    // col octet: cols sub*8..+7
    const int head = (H == 4) ? (sub >> 2) : 0;    // 32 cols per head
    const __half* fb = feat + sub * 8;

    float o0 = 0.f, o1 = 0.f, o2 = 0.f, o3 = 0.f;
    float o4 = 0.f, o5 = 0.f, o6 = 0.f, o7 = 0.f;
    float ssum = 0.f;

    auto accum8 = [&](const __half* hp, float aa) {
        ssum += aa;
        o0 = fmaf(aa, __half2float(hp[0]), o0);
        o1 = fmaf(aa, __half2float(hp[1]), o1);
        o2 = fmaf(aa, __half2float(hp[2]), o2);
        o3 = fmaf(aa, __half2float(hp[3]), o3);
        o4 = fmaf(aa, __half2float(hp[4]), o4);
        o5 = fmaf(aa, __half2float(hp[5]), o5);
        o6 = fmaf(aa, __half2float(hp[6]), o6);
        o7 = fmaf(aa, __half2float(hp[7]), o7);
    };

    for (int cbeg = beg; cbeg < end; cbeg += 64) {
        int cnt = end - cbeg; if (cnt > 64) cnt = 64;
        if (lane < cnt) {
            int j = esrc[cbeg + lane];
            sj[wave][lane] = j;
            if (H == 4) {
                float4 av = *(const float4*)(asrc + (size_t)j * 4);
                float e;
                e = av.x + adst_i[0]; e = e > 0.f ? e : 0.2f * e; sp[wave][0 * 64 + lane] = __expf(e);
                e = av.y + adst_i[1]; e = e > 0.f ? e : 0.2f * e; sp[wave][1 * 64 + lane] = __expf(e);
                e = av.z + adst_i[2]; e = e > 0.f ? e : 0.2f * e; sp[wave][2 * 64 + lane] = __expf(e);
                e = av.w + adst_i[3]; e = e > 0.f ? e : 0.2f * e; sp[wave][3 * 64 + lane] = __expf(e);
            } else {
                float e = asrc[j] + adst_i[0];
                e = e > 0.f ? e : 0.2f * e;
                sp[wave][lane] = __expf(e);
            }
        }
        asm volatile("s_waitcnt lgkmcnt(0)" ::: "memory");

        // batches of 16 edges: issue 4 gathers back-to-back, then consume.
        for (int b0 = 0; b0 < cnt; b0 += 16) {
            float aa[4]; uint4 hv[4];
#pragma unroll
            for (int u = 0; u < 4; u++) {
                int e  = b0 + 4 * u + g;
                bool ok = e < cnt;
                int ec = ok ? e : 0;
                int j  = sj[wave][ec];
                aa[u]  = ok ? sp[wave][head * 64 + ec] : 0.f;
                hv[u]  = *(const uint4*)(fb + (size_t)j * 128);
            }
            accum8((const __half*)&hv[0], aa[0]);
            accum8((const __half*)&hv[1], aa[1]);
            accum8((const __half*)&hv[2], aa[2]);
            accum8((const __half*)&hv[3], aa[3]);
        }
        // same-wave lockstep: staging of the next chunk cannot race these reads
    }

    // reduce across the 4 edge-groups: butterfly leaves full sums in ALL lanes
    o0 += __shfl_xor(o0, 16, 64); o0 += __shfl_xor(o0, 32, 64);
    o1 += __shfl_xor(o1, 16, 64); o1 += __shfl_xor(o1, 32, 64);
    o2 += __shfl_xor(o2, 16, 64); o2 += __shfl_xor(o2, 32, 64);
    o3 += __shfl_xor(o3, 16, 64); o3 += __shfl_xor(o3, 32, 64);
    o4 += __shfl_xor(o4, 16, 64); o4 += __shfl_xor(o4, 32, 64);
    o5 += __shfl_xor(o5, 16, 64); o5 += __shfl_xor(o5, 32, 64);
    o6 += __shfl_xor(o6, 16, 64); o6 += __shfl_xor(o6, 32, 64);
    o7 += __shfl_xor(o7, 16, 64); o7 += __shfl_xor(o7, 32, 64);
    ssum += __shfl_xor(ssum, 16, 64);
    ssum += __shfl_xor(ssum, 32, 64);

    // wave-parallel epilogue: lane finalizes cols sub*8+2g, +1 (SSA selects)
    float so0 = o0, so1 = o1;
    so0 = (g == 1) ? o2 : so0;  so1 = (g == 1) ? o3 : so1;
    so0 = (g == 2) ? o4 : so0;  so1 = (g == 2) ? o5 : so1;
    so0 = (g == 3) ? o6 : so0;  so1 = (g == 3) ? o7 : so1;

    const int c2 = sub * 8 + 2 * g;
    float inv = 1.f / (ssum + 1e-16f);
    float r0 = so0 * inv + bias[c2];
    float r1 = so1 * inv + bias[c2 + 1];
    float e0 = __expf(r0) - 1.0f;                  // cheap ELU (abs err ~1e-6)
    float e1 = __expf(r1) - 1.0f;
    r0 = r0 > 0.f ? r0 : e0;
    r1 = r1 > 0.f ? r1 : e1;

    if constexpr (sizeof(TO) == 2) {
        *(__half2*)((__half*)out + (size_t)node * 128 + c2) = __floats2half2_rn(r0, r1);
    } else {
        *(float2*)((float*)out + (size_t)node * 128 + c2) = make_float2(r0, r1);
    }
}

// ---------------- launch ----------------

extern "C" void kernel_launch(void* const* d_in, const int* in_sizes, int n_in,
                              void* d_out, int out_size, void* d_ws, size_t ws_size,
                              hipStream_t stream)
{
    const float* x    = (const float*)d_in[0];
    const int*   a    = (const int*)  d_in[1];
    const float* W1   = (const float*)d_in[2];
    const float* as1w = (const float*)d_in[3];
    const float* ad1w = (const float*)d_in[4];
    const float* b1   = (const float*)d_in[5];
    const float* W2   = (const float*)d_in[6];
    const float* as2w = (const float*)d_in[7];
    const float* ad2w = (const float*)d_in[8];
    const float* b2   = (const float*)d_in[9];

    const int N = in_sizes[0] / 128;
    const int E = in_sizes[1] / 2;
    const int* srcA = a;
    const int* dstA = a + E;

    char* ws = (char*)d_ws;
    size_t o = 0;
    auto alloc = [&](size_t bytes) -> void* {
        void* p = ws + o;
        o += (bytes + 255) & ~(size_t)255;
        return p;
    };
    __half* hbuf  = (__half*)alloc((size_t)N * 128 * 2);  // GEMM1 out (gather payload 1)
    __half* hact  = (__half*)alloc((size_t)N * 128 * 2);  // elu(gat1) fp16, GEMM2 input
    float*  as1   = (float*) alloc((size_t)N * 4 * 4);
    float*  ad1   = (float*) alloc((size_t)N * 4 * 4);
    float*  as2   = (float*) alloc((size_t)N * 4);
    float*  ad2   = (float*) alloc((size_t)N * 4);
    int*    off   = (int*)   alloc((size_t)(N + 1) * 4);
    int*    esrc  = (int*)   alloc((size_t)E * 4);
    int*    cnt   = (int*)   alloc((size_t)N * 4);
    int*    cur   = (int*)   alloc((size_t)N * 4);
    int*    bsum  = (int*)   alloc(1024 * 4);
    int*    bbase = (int*)   alloc(1024 * 4);

    const int nb = (N + 1023) >> 10;   // <= 1024 assumed (N <= 1M)

    // CSR build (lean 3-pass; rebuilt each launch, ws is re-poisoned)
    hipMemsetAsync(cnt, 0, (size_t)N * 4, stream);
    k_count<<<256, 256, 0, stream>>>(dstA, cnt, E);
    k_ssum<<<nb, 1024, 0, stream>>>(cnt, bsum, N);
    k_stop<<<1, 1024, 0, stream>>>(bsum, bbase, nb, N, E, off);
    k_sfin<<<nb, 1024, 0, stream>>>(cnt, bbase, off, cur, N);
    k_scatter<<<512, 256, 0, stream>>>(srcA, dstA, cur, esrc, E);

    // layer 1 (MFMA GEMM + fused attdot, fp16 Y)
    k_gemm_mfma<4, float><<<768, 256, 0, stream>>>(x, W1, as1w, ad1w, hbuf, as1, ad1, N);
    k_agg<4, __half><<<(N + 3) / 4, 256, 0, stream>>>(hbuf, as1, ad1, off, esrc, b1, hact, N);

    // layer 2
    k_gemm_mfma<1, __half><<<768, 256, 0, stream>>>(hact, W2, as2w, ad2w, hbuf, as2, ad2, N);
    k_agg<1, float><<<(N + 3) / 4, 256, 0, stream>>>(hbuf, as2, ad2, off, esrc, b2, (float*)d_out, N);
}

// Round 14
// 406.111 us; speedup vs baseline: 1.2203x; 1.2203x over previous
//
#include <hip/hip_runtime.h>
#include <hip/hip_fp16.h>
#include <math.h>

// ---------------------------------------------------------------------------
// GAT graph encoder: 2x GATConv (PyG semantics, add_self_loops=False)
// R17->R18: CSR reverted to R15 bucket form (R17's direct-scatter = 155us of
//   random global atomic RMW; bucket CSR is only ~30-50us total -> "CSR
//   dominant" hypothesis dead). NEW: W staging removed from the GEMMs.
//   k_wconv converts W1/W2 once to fragment-major fp16 (global); GEMM
//   blocks load B-frags straight from global (coalesced dwordx4, L2-hot
//   32KB) - deletes 768x per-block 64KB uncoalesced W re-read + convert +
//   barrier, LDS 66->17KB. k_agg (R15 form) untouched as the attribution
//   control (~71.5us each, gather-rate floor).
// ---------------------------------------------------------------------------

typedef _Float16 f16x8 __attribute__((ext_vector_type(8)));
typedef float    f32x4 __attribute__((ext_vector_type(4)));

// ---------------- CSR build (R15 bucket form) ----------------

__global__ __launch_bounds__(256) void k_hist(const int* __restrict__ dst,
                                              int* __restrict__ bcnt, int E, int NBUCK) {
    __shared__ int lh[1024];
    int t = threadIdx.x;
    for (int i = t; i < NBUCK; i += 256) lh[i] = 0;
    __syncthreads();
    for (int e = blockIdx.x * 256 + t; e < E; e += gridDim.x * 256)
        atomicAdd(&lh[dst[e] >> 7], 1);
    __syncthreads();
    for (int i = t; i < NBUCK; i += 256) {
        int c = lh[i];
        if (c) atomicAdd(&bcnt[i], c);
    }
}

__global__ void k_bscan(const int* __restrict__ bcnt, int* __restrict__ bbase,
                        int* __restrict__ bcur, int* __restrict__ off,
                        int NBUCK, int N, int E) {
    __shared__ int sd[1024];
    int t = threadIdx.x;
    int v = (t < NBUCK) ? bcnt[t] : 0;
    sd[t] = v; __syncthreads();
    for (int ofs = 1; ofs < 1024; ofs <<= 1) {
        int w = (t >= ofs) ? sd[t - ofs] : 0;
        __syncthreads();
        sd[t] += w;
        __syncthreads();
    }
    if (t < NBUCK) { int ex = sd[t] - v; bbase[t] = ex; bcur[t] = ex; }
    if (t == 0) { bbase[NBUCK] = E; off[N] = E; }
}

__global__ __launch_bounds__(256) void k_binscatter(
    const int* __restrict__ src, const int* __restrict__ dst,
    int* __restrict__ bcur, int* __restrict__ tmp, int E, int NBUCK) {
    __shared__ int lh[1024], lbase[1024];
    int t = threadIdx.x;
    for (int i = t; i < NBUCK; i += 256) lh[i] = 0;
    __syncthreads();
    int tbeg = blockIdx.x * 8192;
    int tend = tbeg + 8192; if (tend > E) tend = E;
    for (int e = tbeg + t; e < tend; e += 256) atomicAdd(&lh[dst[e] >> 7], 1);
    __syncthreads();
    for (int i = t; i < NBUCK; i += 256) {
        int c = lh[i];
        lbase[i] = c ? atomicAdd(&bcur[i], c) : 0;
        lh[i] = 0;
    }
    __syncthreads();
    for (int e = tbeg + t; e < tend; e += 256) {
        int d = dst[e];
        int b = d >> 7;
        int r = atomicAdd(&lh[b], 1);
        tmp[lbase[b] + r] = (src[e] << 7) | (d & 127);
    }
}

__global__ __launch_bounds__(256) void k_bsort(
    const int* __restrict__ tmp, const int* __restrict__ bbase,
    int* __restrict__ off, int* __restrict__ esrc, int N) {
    __shared__ int h[128], hs[128], cur[128];
    int b = blockIdx.x, t = threadIdx.x;
    int base = bbase[b];
    int cnt  = bbase[b + 1] - base;
    int node0 = b << 7;
    if (t < 128) h[t] = 0;
    __syncthreads();
    for (int i = t; i < cnt; i += 256) atomicAdd(&h[tmp[base + i] & 127], 1);
    __syncthreads();
    if (t < 128) hs[t] = h[t];
    __syncthreads();
    for (int ofs = 1; ofs < 128; ofs <<= 1) {
        int w = (t < 128 && t >= ofs) ? hs[t - ofs] : 0;
        __syncthreads();
        if (t < 128) hs[t] += w;
        __syncthreads();
    }
    if (t < 128) {
        int ex = hs[t] - h[t];
        if (node0 + t < N) off[node0 + t] = base + ex;
        cur[t] = base + ex;
    }
    __syncthreads();
    for (int i = t; i < cnt; i += 256) {
        int p = tmp[base + i];
        int pos = atomicAdd(&cur[p & 127], 1);
        esrc[pos] = p >> 7;
    }
}

// ---------------- W -> fragment-major fp16 (once) ----------------
// Wf[(nt*4+ks)*512 + ((q<<4)|m)*8 + j] = W[(ks*32+q*8+j)*128 + nt*16+m]

__global__ __launch_bounds__(256) void k_wconv(const float* __restrict__ W1,
                                               const float* __restrict__ W2,
                                               _Float16* __restrict__ W1f,
                                               _Float16* __restrict__ W2f) {
    int i = blockIdx.x * 256 + threadIdx.x;   // 0..16383 (k*128+col)
    if (i < 16384) {
        int k = i >> 7, col = i & 127;
        int nt = col >> 4, m = col & 15;
        int ks = k >> 5, q = (k >> 3) & 3, j = k & 7;
        int dest = (nt * 4 + ks) * 512 + ((q << 4) | m) * 8 + j;
        W1f[dest] = (_Float16)W1[i];
        W2f[dest] = (_Float16)W2[i];
    }
}

// ---------------- MFMA GEMM + fused attention dots ----------------
// Y(fp16)[N,128] = cast16(X[N,128]) @ cast16(W[128,128]); fp32 accum.
// A-frag: m=lane&15 (row), k=(lane>>4)*8+j. B-frag: n=lane&15 (col), same k.
// C/D: col=lane&15, row=(lane>>4)*4+reg.
// R18: B-frags loaded directly from global fragment-major Wf (coalesced
// dwordx4, L2-hot); no W LDS, no staging barrier. LDS = Xh only (17KB).

template <int H, typename TI>
__global__ __launch_bounds__(256, 3) void k_gemm_mfma(
    const TI* __restrict__ X, const _Float16* __restrict__ Wf,
    const float* __restrict__ att_s, const float* __restrict__ att_d,
    __half* __restrict__ Y, float* __restrict__ as_, float* __restrict__ ad_, int N)
{
    __shared__ _Float16 Xh[64][136];     // +8 pad: breaks 256B-stride bank clash
    const int t = threadIdx.x;
    const int lane = t & 63;
    const int wv = t >> 6;
    const int m = lane & 15;
    const int q = lane >> 4;

    float atts_v[8], attd_v[8];
#pragma unroll
    for (int nt = 0; nt < 8; nt++) {
        atts_v[nt] = att_s[nt * 16 + m];
        attd_v[nt] = att_d[nt * 16 + m];
    }

    for (int base = blockIdx.x * 64; base < N; base += gridDim.x * 64) {
        // stage 64 rows of X -> fp16 LDS (1024 chunks of 8 halfs, 4/thread)
        for (int i = t; i < 1024; i += 256) {
            int r = i >> 4, c8 = i & 15;
            int gr = base + r;
            _Float16* d = &Xh[r][c8 * 8];
            if (gr < N) {
                if constexpr (sizeof(TI) == 4) {
                    const float4* s = (const float4*)((const float*)X + (size_t)gr * 128 + c8 * 8);
                    float4 x0 = s[0], x1 = s[1];
                    d[0] = (_Float16)x0.x; d[1] = (_Float16)x0.y;
                    d[2] = (_Float16)x0.z; d[3] = (_Float16)x0.w;
                    d[4] = (_Float16)x1.x; d[5] = (_Float16)x1.y;
                    d[6] = (_Float16)x1.z; d[7] = (_Float16)x1.w;
                } else {
                    *(uint4*)d = *(const uint4*)((const __half*)X + (size_t)gr * 128 + c8 * 8);
                }
            } else {
                uint4 z; z.x = 0; z.y = 0; z.z = 0; z.w = 0;
                *(uint4*)d = z;
            }
        }
        __syncthreads();

        const int rowb = base + wv * 16;

        // A-fragments for this wave's 16 rows (4 x ds_read_b128)
        f16x8 af[4];
#pragma unroll
        for (int ks = 0; ks < 4; ks++)
            af[ks] = *(const f16x8*)&Xh[wv * 16 + m][ks * 32 + q * 8];

        f32x4 acc[8];
#pragma unroll
        for (int nt = 0; nt < 8; nt++) { acc[nt][0] = 0.f; acc[nt][1] = 0.f; acc[nt][2] = 0.f; acc[nt][3] = 0.f; }

        // B-frags straight from global Wf (coalesced 16B/lane, L2-hot)
#pragma unroll
        for (int nt = 0; nt < 8; nt++) {
            f16x8 b0v = *(const f16x8*)(Wf + (size_t)(nt * 4 + 0) * 512 + lane * 8);
            f16x8 b1v = *(const f16x8*)(Wf + (size_t)(nt * 4 + 1) * 512 + lane * 8);
            f16x8 b2v = *(const f16x8*)(Wf + (size_t)(nt * 4 + 2) * 512 + lane * 8);
            f16x8 b3v = *(const f16x8*)(Wf + (size_t)(nt * 4 + 3) * 512 + lane * 8);
            acc[nt] = __builtin_amdgcn_mfma_f32_16x16x32_f16(af[0], b0v, acc[nt], 0, 0, 0);
            acc[nt] = __builtin_amdgcn_mfma_f32_16x16x32_f16(af[1], b1v, acc[nt], 0, 0, 0);
            acc[nt] = __builtin_amdgcn_mfma_f32_16x16x32_f16(af[2], b2v, acc[nt], 0, 0, 0);
            acc[nt] = __builtin_amdgcn_mfma_f32_16x16x32_f16(af[3], b3v, acc[nt], 0, 0, 0);
        }

        // Y writes (fp16 scalar stores; C-layout)
#pragma unroll
        for (int nt = 0; nt < 8; nt++) {
#pragma unroll
            for (int i = 0; i < 4; i++) {
                int r = rowb + q * 4 + i;
                if (r < N) Y[(size_t)r * 128 + nt * 16 + m] = __float2half(acc[nt][i]);
            }
        }

        // fused attention dots: per-lane partials, butterfly over the 16 cols
        if (H == 4) {
            float ph[4][4], pdv[4][4];
#pragma unroll
            for (int h = 0; h < 4; h++)
#pragma unroll
                for (int i = 0; i < 4; i++) {
                    ph[h][i]  = acc[2 * h][i] * atts_v[2 * h] + acc[2 * h + 1][i] * atts_v[2 * h + 1];
                    pdv[h][i] = acc[2 * h][i] * attd_v[2 * h] + acc[2 * h + 1][i] * attd_v[2 * h + 1];
                }
#pragma unroll
            for (int lvl = 0; lvl < 4; lvl++) {
                const int msk = 1 << lvl;
#pragma unroll
                for (int h = 0; h < 4; h++)
#pragma unroll
                    for (int i = 0; i < 4; i++) {
                        ph[h][i]  += __shfl_xor(ph[h][i], msk, 64);
                        pdv[h][i] += __shfl_xor(pdv[h][i], msk, 64);
                    }
            }
            if (m == 0) {
#pragma unroll
                for (int i = 0; i < 4; i++) {
                    int r = rowb + q * 4 + i;
                    if (r < N) {
#pragma unroll
                        for (int h = 0; h < 4; h++) {
                            as_[(size_t)r * 4 + h] = ph[h][i];
                            ad_[(size_t)r * 4 + h] = pdv[h][i];
                        }
                    }
                }
            }
        } else {
            float ps[4], pdv[4];
#pragma unroll
            for (int i = 0; i < 4; i++) {
                float s = 0.f, dsum = 0.f;
#pragma unroll
                for (int nt = 0; nt < 8; nt++) {
                    s    += acc[nt][i] * atts_v[nt];
                    dsum += acc[nt][i] * attd_v[nt];
                }
                ps[i] = s; pdv[i] = dsum;
            }
#pragma unroll
            for (int lvl = 0; lvl < 4; lvl++) {
                const int msk = 1 << lvl;
#pragma unroll
                for (int i = 0; i < 4; i++) {
                    ps[i]  += __shfl_xor(ps[i], msk, 64);
                    pdv[i] += __shfl_xor(pdv[i], msk, 64);
                }
            }
            if (m == 0) {
#pragma unroll
                for (int i = 0; i < 4; i++) {
                    int r = rowb + q * 4 + i;
                    if (r < N) { as_[r] = ps[i]; ad_[r] = pdv[i]; }
                }
            }
        }
        __syncthreads();   // protect Xh before next tile's staging
    }
}

// ---------------- aggregation: one wave per dst node (R15 form) ----------------
// 16 lanes per edge at 16B/lane; batches of 16 edges, 4 uint4 loads issued
// before consumption; tail predicated. Accumulator = 8 named scalars (no
// alloca -> no PromoteAlloca-to-LDS). Wave-parallel epilogue: each lane
// finalizes 2 cols via cndmask selection on SSA scalars. Cheap ELU.

template <int H, typename TO>
__global__ __launch_bounds__(256) void k_agg(
    const __half* __restrict__ feat,  // [N,128] fp16
    const float* __restrict__ asrc,   // [N,H]
    const float* __restrict__ adst,   // [N,H]
    const int*   __restrict__ off,    // [N+1]
    const int*   __restrict__ esrc,   // [E]
    const float* __restrict__ bias,   // [128]
    TO*          __restrict__ out,    // [N,128]
    int N)
{
    __shared__ __attribute__((aligned(16))) int   sj[4][64];
    __shared__ __attribute__((aligned(16))) float sp[4][64 * H];  // head-major

    int wave = threadIdx.x >> 6;
    int lane = threadIdx.x & 63;
    int node = (blockIdx.x * 256 + threadIdx.x) >> 6;
    if (node >= N) return;
    int beg = off[node], end = off[node + 1];

    float adst_i[H];
#pragma unroll
    for (int h = 0; h < H; h++) adst_i[h] = adst[(size_t)node * H + h];

    const int g    = lane >> 4;                    // edge sub-slot 0..3
    const int sub  = lane & 15;                    // col octet: cols sub*8..+7
    const int head = (H == 4) ? (sub >> 2) : 0;    // 32 cols per head
    const __half* fb = feat + sub * 8;

    float o0 = 0.f, o1 = 0.f, o2 = 0.f, o3 = 0.f;
    float o4 = 0.f, o5 = 0.f, o6 = 0.f, o7 = 0.f;
    float ssum = 0.f;

    auto accum8 = [&](const __half* hp, float aa) {
        ssum += aa;
        o0 = fmaf(aa, __half2float(hp[0]), o0);
        o1 = fmaf(aa, __half2float(hp[1]), o1);
        o2 = fmaf(aa, __half2float(hp[2]), o2);
        o3 = fmaf(aa, __half2float(hp[3]), o3);
        o4 = fmaf(aa, __half2float(hp[4]), o4);
        o5 = fmaf(aa, __half2float(hp[5]), o5);
        o6 = fmaf(aa, __half2float(hp[6]), o6);
        o7 = fmaf(aa, __half2float(hp[7]), o7);
    };

    for (int cbeg = beg; cbeg < end; cbeg += 64) {
        int cnt = end - cbeg; if (cnt > 64) cnt = 64;
        if (lane < cnt) {
            int j = esrc[cbeg + lane];
            sj[wave][lane] = j;
            if (H == 4) {
                float4 av = *(const float4*)(asrc + (size_t)j * 4);
                float e;
                e = av.x + adst_i[0]; e = e > 0.f ? e : 0.2f * e; sp[wave][0 * 64 + lane] = __expf(e);
                e = av.y + adst_i[1]; e = e > 0.f ? e : 0.2f * e; sp[wave][1 * 64 + lane] = __expf(e);
                e = av.z + adst_i[2]; e = e > 0.f ? e : 0.2f * e; sp[wave][2 * 64 + lane] = __expf(e);
                e = av.w + adst_i[3]; e = e > 0.f ? e : 0.2f * e; sp[wave][3 * 64 + lane] = __expf(e);
            } else {
                float e = asrc[j] + adst_i[0];
                e = e > 0.f ? e : 0.2f * e;
                sp[wave][lane] = __expf(e);
            }
        }
        asm volatile("s_waitcnt lgkmcnt(0)" ::: "memory");

        // batches of 16 edges: issue 4 gathers back-to-back, then consume.
        for (int b0 = 0; b0 < cnt; b0 += 16) {
            float aa[4]; uint4 hv[4];
#pragma unroll
            for (int u = 0; u < 4; u++) {
                int e  = b0 + 4 * u + g;
                bool ok = e < cnt;
                int ec = ok ? e : 0;
                int j  = sj[wave][ec];
                aa[u]  = ok ? sp[wave][head * 64 + ec] : 0.f;
                hv[u]  = *(const uint4*)(fb + (size_t)j * 128);
            }
            accum8((const __half*)&hv[0], aa[0]);
            accum8((const __half*)&hv[1], aa[1]);
            accum8((const __half*)&hv[2], aa[2]);
            accum8((const __half*)&hv[3], aa[3]);
        }
        // same-wave lockstep: staging of the next chunk cannot race these reads
    }

    // reduce across the 4 edge-groups: butterfly leaves full sums in ALL lanes
    o0 += __shfl_xor(o0, 16, 64); o0 += __shfl_xor(o0, 32, 64);
    o1 += __shfl_xor(o1, 16, 64); o1 += __shfl_xor(o1, 32, 64);
    o2 += __shfl_xor(o2, 16, 64); o2 += __shfl_xor(o2, 32, 64);
    o3 += __shfl_xor(o3, 16, 64); o3 += __shfl_xor(o3, 32, 64);
    o4 += __shfl_xor(o4, 16, 64); o4 += __shfl_xor(o4, 32, 64);
    o5 += __shfl_xor(o5, 16, 64); o5 += __shfl_xor(o5, 32, 64);
    o6 += __shfl_xor(o6, 16, 64); o6 += __shfl_xor(o6, 32, 64);
    o7 += __shfl_xor(o7, 16, 64); o7 += __shfl_xor(o7, 32, 64);
    ssum += __shfl_xor(ssum, 16, 64);
    ssum += __shfl_xor(ssum, 32, 64);

    // wave-parallel epilogue: lane finalizes cols sub*8+2g, +1 (SSA selects)
    float so0 = o0, so1 = o1;
    so0 = (g == 1) ? o2 : so0;  so1 = (g == 1) ? o3 : so1;
    so0 = (g == 2) ? o4 : so0;  so1 = (g == 2) ? o5 : so1;
    so0 = (g == 3) ? o6 : so0;  so1 = (g == 3) ? o7 : so1;

    const int c2 = sub * 8 + 2 * g;
    float inv = 1.f / (ssum + 1e-16f);
    float r0 = so0 * inv + bias[c2];
    float r1 = so1 * inv + bias[c2 + 1];
    float e0 = __expf(r0) - 1.0f;                  // cheap ELU (abs err ~1e-6)
    float e1 = __expf(r1) - 1.0f;
    r0 = r0 > 0.f ? r0 : e0;
    r1 = r1 > 0.f ? r1 : e1;

    if constexpr (sizeof(TO) == 2) {
        *(__half2*)((__half*)out + (size_t)node * 128 + c2) = __floats2half2_rn(r0, r1);
    } else {
        *(float2*)((float*)out + (size_t)node * 128 + c2) = make_float2(r0, r1);
    }
}

// ---------------- launch ----------------

extern "C" void kernel_launch(void* const* d_in, const int* in_sizes, int n_in,
                              void* d_out, int out_size, void* d_ws, size_t ws_size,
                              hipStream_t stream)
{
    const float* x    = (const float*)d_in[0];
    const int*   a    = (const int*)  d_in[1];
    const float* W1   = (const float*)d_in[2];
    const float* as1w = (const float*)d_in[3];
    const float* ad1w = (const float*)d_in[4];
    const float* b1   = (const float*)d_in[5];
    const float* W2   = (const float*)d_in[6];
    const float* as2w = (const float*)d_in[7];
    const float* ad2w = (const float*)d_in[8];
    const float* b2   = (const float*)d_in[9];

    const int N = in_sizes[0] / 128;
    const int E = in_sizes[1] / 2;
    const int* srcA = a;
    const int* dstA = a + E;
    const int NBUCK = (N + 127) >> 7;

    char* ws = (char*)d_ws;
    size_t o = 0;
    auto alloc = [&](size_t bytes) -> void* {
        void* p = ws + o;
        o += (bytes + 255) & ~(size_t)255;
        return p;
    };
    __half*    hbuf = (__half*)   alloc((size_t)N * 128 * 2);  // GEMM1 out (gather payload 1)
    __half*    hact = (__half*)   alloc((size_t)N * 128 * 2);  // elu(gat1) fp16, GEMM2 input
    float*     as1  = (float*)    alloc((size_t)N * 4 * 4);
    float*     ad1  = (float*)    alloc((size_t)N * 4 * 4);
    float*     as2  = (float*)    alloc((size_t)N * 4);
    float*     ad2  = (float*)    alloc((size_t)N * 4);
    int*       off  = (int*)      alloc((size_t)(N + 1) * 4);
    int*       esrc = (int*)      alloc((size_t)E * 4);
    int*       tmp  = (int*)      alloc((size_t)E * 4);
    int*       bcnt = (int*)      alloc(1024 * 4);
    int*       bbase= (int*)      alloc(1025 * 4);
    int*       bcur = (int*)      alloc(1024 * 4);
    _Float16*  w1f  = (_Float16*) alloc((size_t)16384 * 2);    // fragment-major W1 fp16
    _Float16*  w2f  = (_Float16*) alloc((size_t)16384 * 2);    // fragment-major W2 fp16

    // W conversion (once) + CSR build (rebuilt each launch; ws re-poisoned)
    k_wconv<<<64, 256, 0, stream>>>(W1, W2, w1f, w2f);
    hipMemsetAsync(bcnt, 0, (size_t)NBUCK * 4, stream);
    k_hist<<<256, 256, 0, stream>>>(dstA, bcnt, E, NBUCK);
    k_bscan<<<1, 1024, 0, stream>>>(bcnt, bbase, bcur, off, NBUCK, N, E);
    k_binscatter<<<(E + 8191) / 8192, 256, 0, stream>>>(srcA, dstA, bcur, tmp, E, NBUCK);
    k_bsort<<<NBUCK, 256, 0, stream>>>(tmp, bbase, off, esrc, N);

    // layer 1 (MFMA GEMM + fused attdot, fp16 Y)
    k_gemm_mfma<4, float><<<768, 256, 0, stream>>>(x, w1f, as1w, ad1w, hbuf, as1, ad1, N);
    k_agg<4, __half><<<(N + 3) / 4, 256, 0, stream>>>(hbuf, as1, ad1, off, esrc, b1, hact, N);

    // layer 2
    k_gemm_mfma<1, __half><<<768, 256, 0, stream>>>(hact, w2f, as2w, ad2w, hbuf, as2, ad2, N);
    k_agg<1, float><<<(N + 3) / 4, 256, 0, stream>>>(hbuf, as2, ad2, off, esrc, b2, (float*)d_out, N);
}